// Round 1
// baseline (150.428 us; speedup 1.0000x reference)
//
#include <hip/hip_runtime.h>

static constexpr int BASE = 512;

// float offsets of each level in the (h,w,16)-layout pyramid
__constant__ int d_off[8] = {0, 4194304, 5242880, 5505024, 5570560, 5586944, 5591040, 5592064};
// total floats = 5592320 -> 22,369,280 bytes of ws

// ---------------- Kernel A1: transpose (C,512,512) -> (512,512,C) ----------------
__global__ void transpose_l0(const float* __restrict__ tex, float* __restrict__ dst) {
    int pix = blockIdx.x * blockDim.x + threadIdx.x;   // 0..262143, grid sized exactly
    float v[16];
#pragma unroll
    for (int c = 0; c < 16; ++c) v[c] = tex[c * 262144 + pix];
    float4* o = (float4*)(dst + (size_t)pix * 16);
    o[0] = make_float4(v[0], v[1], v[2], v[3]);
    o[1] = make_float4(v[4], v[5], v[6], v[7]);
    o[2] = make_float4(v[8], v[9], v[10], v[11]);
    o[3] = make_float4(v[12], v[13], v[14], v[15]);
}

// ---------------- Kernel A2: build levels 1..7 from transposed L0 ----------------
// Reference resize (align_corners=False, scale 2^l) reduces to:
//   out[y][x] = yinterp-then-xinterp 2x2 average at (yy,xx), yy=(y<<l)+(1<<(l-1))-1
__global__ void build_levels(const float* __restrict__ l0, float* __restrict__ ws) {
    int lev = blockIdx.y + 1;            // 1..7
    int w = BASE >> lev;
    int npix = w * w;
    int pix = blockIdx.x * blockDim.x + threadIdx.x;
    if (pix >= npix) return;
    int y = pix >> (9 - lev);            // pix / w
    int x = pix & (w - 1);
    int xx = (x << lev) + (1 << (lev - 1)) - 1;
    int yy = (y << lev) + (1 << (lev - 1)) - 1;
    const float4* t = (const float4*)l0;
    float4* dst = (float4*)(ws + d_off[lev] + (size_t)pix * 16);
    int i00 = (yy * 512 + xx) * 4;
    int i01 = i00 + 4;
    int i10 = i00 + 512 * 4;
    int i11 = i10 + 4;
#pragma unroll
    for (int q = 0; q < 4; ++q) {
        float4 a = t[i00 + q];   // v00 (yy , xx )
        float4 b = t[i01 + q];   // v01 (yy , xx+1)
        float4 c = t[i10 + q];   // v10 (yy+1, xx )
        float4 d = t[i11 + q];   // v11 (yy+1, xx+1)
        float4 r;
        r.x = (a.x * 0.5f + c.x * 0.5f) * 0.5f + (b.x * 0.5f + d.x * 0.5f) * 0.5f;
        r.y = (a.y * 0.5f + c.y * 0.5f) * 0.5f + (b.y * 0.5f + d.y * 0.5f) * 0.5f;
        r.z = (a.z * 0.5f + c.z * 0.5f) * 0.5f + (b.z * 0.5f + d.z * 0.5f) * 0.5f;
        r.w = (a.w * 0.5f + c.w * 0.5f) * 0.5f + (b.w * 0.5f + d.w * 0.5f) * 0.5f;
        dst[q] = r;
    }
}

// ---------------- Kernel B: trilinear mip sampling ----------------
// 4 threads per query; thread q handles channels [4q, 4q+4).
__global__ void sample_kernel(const float* __restrict__ uv, const float* __restrict__ p,
                              const float* __restrict__ ws, float* __restrict__ out, int N) {
    int tid = blockIdx.x * blockDim.x + threadIdx.x;
    int n = tid >> 2;
    int q = tid & 3;
    if (n >= N) return;

    float u0 = uv[2 * n];
    float v0 = uv[2 * n + 1];
    float pp = p[n];
    float gx = 2.0f * u0 - 1.0f;
    float gy = 2.0f * v0 - 1.0f;

    float lf = pp * 7.0f;
    int l0 = (int)floorf(lf);
    l0 = max(0, min(l0, 7));
    int l1 = min(l0 + 1, 7);
    float alpha = lf - (float)l0;

    float4 r[2];
    int ls[2] = {l0, l1};
#pragma unroll
    for (int k = 0; k < 2; ++k) {
        int l = ls[k];
        int w = BASE >> l;
        float wm1 = (float)(w - 1);
        float x = (gx + 1.0f) * 0.5f * wm1;
        x = fminf(fmaxf(x, 0.0f), wm1);
        float y = (gy + 1.0f) * 0.5f * wm1;
        y = fminf(fmaxf(y, 0.0f), wm1);
        int x0 = (int)x;                  // x >= 0, trunc == floor
        int y0 = (int)y;
        x0 = min(x0, w - 1);
        y0 = min(y0, w - 1);
        int x1 = min(x0 + 1, w - 1);
        int y1 = min(y0 + 1, w - 1);
        float fx = x - (float)x0;
        float fy = y - (float)y0;

        const float4* t = (const float4*)(ws + d_off[l]);
        float4 v00 = t[(y0 * w + x0) * 4 + q];
        float4 v01 = t[(y0 * w + x1) * 4 + q];
        float4 v10 = t[(y1 * w + x0) * 4 + q];
        float4 v11 = t[(y1 * w + x1) * 4 + q];

        float w00 = (1.0f - fx) * (1.0f - fy);
        float w01 = fx * (1.0f - fy);
        float w10 = (1.0f - fx) * fy;
        float w11 = fx * fy;
        r[k].x = v00.x * w00 + v01.x * w01 + v10.x * w10 + v11.x * w11;
        r[k].y = v00.y * w00 + v01.y * w01 + v10.y * w10 + v11.y * w11;
        r[k].z = v00.z * w00 + v01.z * w01 + v10.z * w10 + v11.z * w11;
        r[k].w = v00.w * w00 + v01.w * w01 + v10.w * w10 + v11.w * w11;
    }

    float4 o;
    o.x = r[0].x * (1.0f - alpha) + r[1].x * alpha;
    o.y = r[0].y * (1.0f - alpha) + r[1].y * alpha;
    o.z = r[0].z * (1.0f - alpha) + r[1].z * alpha;
    o.w = r[0].w * (1.0f - alpha) + r[1].w * alpha;
    ((float4*)out)[n * 4 + q] = o;
}

extern "C" void kernel_launch(void* const* d_in, const int* in_sizes, int n_in,
                              void* d_out, int out_size, void* d_ws, size_t ws_size,
                              hipStream_t stream) {
    const float* uv  = (const float*)d_in[0];
    const float* p   = (const float*)d_in[1];
    const float* tex = (const float*)d_in[2];
    float* out = (float*)d_out;
    float* ws  = (float*)d_ws;
    int N = in_sizes[1];

    // A1: transpose base level into ws (262144 pixels, exact grid)
    transpose_l0<<<262144 / 256, 256, 0, stream>>>(tex, ws);

    // A2: build levels 1..7 (level 1 has 65536 pixels -> 256 blocks; others early-exit)
    dim3 gA2(256, 7);
    build_levels<<<gA2, 256, 0, stream>>>(ws, ws);

    // B: sample (4 threads per query)
    long long total = (long long)N * 4;
    int blocks = (int)((total + 255) / 256);
    sample_kernel<<<blocks, 256, 0, stream>>>(uv, p, ws, out, N);
}

// Round 3
// 132.208 us; speedup vs baseline: 1.1378x; 1.1378x over previous
//
#include <hip/hip_runtime.h>
#include <hip/hip_fp16.h>

static constexpr int BASE = 512;

// half-element offsets of each level in the (h,w,16)-layout fp16 pyramid
__constant__ int c_off[8] = {0, 4194304, 5242880, 5505024, 5570560, 5586944, 5591040, 5592064};
// total halves = 5592320 -> 11,184,640 bytes of ws

// ---------------- Kernel A1: transpose (C,512,512) fp32 -> (512,512,C) fp16 ----------------
__global__ void transpose_l0(const float* __restrict__ tex, __half* __restrict__ dst) {
    int pix = blockIdx.x * blockDim.x + threadIdx.x;   // grid sized exactly: 262144 threads
    float v[16];
#pragma unroll
    for (int c = 0; c < 16; ++c) v[c] = tex[c * 262144 + pix];
    __half2 h[8];
#pragma unroll
    for (int i = 0; i < 8; ++i) h[i] = __floats2half2_rn(v[2 * i], v[2 * i + 1]);
    float4* o = (float4*)(dst + (size_t)pix * 16);
    o[0] = *(const float4*)&h[0];
    o[1] = *(const float4*)&h[4];
}

// convert one 32B texel (16 halves) to 16 floats
__device__ inline void load_texel16(const __half* p, float* f) {
    float4 r0 = ((const float4*)p)[0];
    float4 r1 = ((const float4*)p)[1];
    const __half2* h0 = (const __half2*)&r0;
    const __half2* h1 = (const __half2*)&r1;
#pragma unroll
    for (int i = 0; i < 4; ++i) {
        float2 a = __half22float2(h0[i]);
        f[2 * i] = a.x; f[2 * i + 1] = a.y;
        float2 b = __half22float2(h1[i]);
        f[8 + 2 * i] = b.x; f[9 + 2 * i] = b.y;
    }
}

// ---------------- Kernel A2: build levels 1..7 from fp16 L0 ----------------
// Reference resize (align_corners=False, pow2 scale) == 2x2 avg at
// yy=(y<<l)+(1<<(l-1))-1, association: (v00*.5+v10*.5)*.5+(v01*.5+v11*.5)*.5
__global__ void build_levels(const __half* __restrict__ l0, __half* __restrict__ ws) {
    int lev = blockIdx.y + 1;            // 1..7
    int w = BASE >> lev;
    int npix = w * w;
    int pix = blockIdx.x * blockDim.x + threadIdx.x;
    if (pix >= npix) return;
    int y = pix >> (9 - lev);
    int x = pix & (w - 1);
    int xx = (x << lev) + (1 << (lev - 1)) - 1;
    int yy = (y << lev) + (1 << (lev - 1)) - 1;
    const __half* b00 = l0 + (size_t)(yy * 512 + xx) * 16;
    float a[16], b[16], c[16], d[16];
    load_texel16(b00, a);                // (yy  , xx  )
    load_texel16(b00 + 16, b);           // (yy  , xx+1)
    load_texel16(b00 + 512 * 16, c);     // (yy+1, xx  )
    load_texel16(b00 + 512 * 16 + 16, d);// (yy+1, xx+1)
    __half2 r[8];
#pragma unroll
    for (int i = 0; i < 8; ++i) {
        float r0 = (a[2 * i] * 0.5f + c[2 * i] * 0.5f) * 0.5f +
                   (b[2 * i] * 0.5f + d[2 * i] * 0.5f) * 0.5f;
        float r1 = (a[2 * i + 1] * 0.5f + c[2 * i + 1] * 0.5f) * 0.5f +
                   (b[2 * i + 1] * 0.5f + d[2 * i + 1] * 0.5f) * 0.5f;
        r[i] = __floats2half2_rn(r0, r1);
    }
    float4* dst = (float4*)(ws + c_off[lev] + (size_t)pix * 16);
    dst[0] = *(const float4*)&r[0];
    dst[1] = *(const float4*)&r[4];
}

// ---------------- Kernel B: trilinear mip sampling ----------------
// 2 threads per query; thread q handles channels [8q, 8q+8).
__global__ void sample_kernel(const float2* __restrict__ uv, const float* __restrict__ p,
                              const __half* __restrict__ ws, float* __restrict__ out, int N) {
    int tid = blockIdx.x * blockDim.x + threadIdx.x;
    int n = tid >> 1;
    int q = tid & 1;
    if (n >= N) return;

    float2 uvn = uv[n];
    float pp = p[n];
    float gx = 2.0f * uvn.x - 1.0f;
    float gy = 2.0f * uvn.y - 1.0f;

    float lf = pp * 7.0f;
    int l0 = (int)lf;                    // lf >= 0
    l0 = min(l0, 7);
    int l1 = min(l0 + 1, 7);
    float alpha = lf - (float)l0;

    float acc[8];
#pragma unroll
    for (int j = 0; j < 8; ++j) acc[j] = 0.0f;

    int ls[2] = {l0, l1};
    float lw[2] = {1.0f - alpha, alpha};
#pragma unroll
    for (int k = 0; k < 2; ++k) {
        int l = ls[k];
        int w = BASE >> l;
        float wm1 = (float)(w - 1);
        float x = (gx + 1.0f) * 0.5f * wm1;
        x = fminf(fmaxf(x, 0.0f), wm1);
        float y = (gy + 1.0f) * 0.5f * wm1;
        y = fminf(fmaxf(y, 0.0f), wm1);
        int x0 = min((int)x, w - 1);
        int y0 = min((int)y, w - 1);
        int x1 = min(x0 + 1, w - 1);
        int y1 = min(y0 + 1, w - 1);
        float fx = x - (float)x0;
        float fy = y - (float)y0;

        const __half* t = ws + c_off[l] + 8 * q;
        float v00[8], v01[8], v10[8], v11[8];
        {
            float4 r00 = *(const float4*)(t + (size_t)(y0 * w + x0) * 16);
            float4 r01 = *(const float4*)(t + (size_t)(y0 * w + x1) * 16);
            float4 r10 = *(const float4*)(t + (size_t)(y1 * w + x0) * 16);
            float4 r11 = *(const float4*)(t + (size_t)(y1 * w + x1) * 16);
            const __half2* h00 = (const __half2*)&r00;
            const __half2* h01 = (const __half2*)&r01;
            const __half2* h10 = (const __half2*)&r10;
            const __half2* h11 = (const __half2*)&r11;
#pragma unroll
            for (int i = 0; i < 4; ++i) {
                float2 a = __half22float2(h00[i]); v00[2 * i] = a.x; v00[2 * i + 1] = a.y;
                float2 b = __half22float2(h01[i]); v01[2 * i] = b.x; v01[2 * i + 1] = b.y;
                float2 c = __half22float2(h10[i]); v10[2 * i] = c.x; v10[2 * i + 1] = c.y;
                float2 d = __half22float2(h11[i]); v11[2 * i] = d.x; v11[2 * i + 1] = d.y;
            }
        }

        float w00 = (1.0f - fx) * (1.0f - fy) * lw[k];
        float w01 = fx * (1.0f - fy) * lw[k];
        float w10 = (1.0f - fx) * fy * lw[k];
        float w11 = fx * fy * lw[k];
#pragma unroll
        for (int j = 0; j < 8; ++j)
            acc[j] += v00[j] * w00 + v01[j] * w01 + v10[j] * w10 + v11[j] * w11;
    }

    float4* o = (float4*)(out + (size_t)n * 16 + 8 * q);
    o[0] = make_float4(acc[0], acc[1], acc[2], acc[3]);
    o[1] = make_float4(acc[4], acc[5], acc[6], acc[7]);
}

extern "C" void kernel_launch(void* const* d_in, const int* in_sizes, int n_in,
                              void* d_out, int out_size, void* d_ws, size_t ws_size,
                              hipStream_t stream) {
    const float* uv  = (const float*)d_in[0];
    const float* p   = (const float*)d_in[1];
    const float* tex = (const float*)d_in[2];
    float* out = (float*)d_out;
    __half* ws = (__half*)d_ws;
    int N = in_sizes[1];

    // A1: transpose+convert base level into ws (262144 pixels, exact grid)
    transpose_l0<<<262144 / 256, 256, 0, stream>>>(tex, ws);

    // A2: build levels 1..7
    dim3 gA2(256, 7);
    build_levels<<<gA2, 256, 0, stream>>>(ws, ws);

    // B: sample (2 threads per query)
    long long total = (long long)N * 2;
    int blocks = (int)((total + 255) / 256);
    sample_kernel<<<blocks, 256, 0, stream>>>((const float2*)uv, p, ws, out, N);
}